// Round 2
// baseline (352.755 us; speedup 1.0000x reference)
//
#include <hip/hip_runtime.h>

// Problem constants (match reference)
#define NPROP 4096
#define NTOK  16777216
#define BLOCK 1024
#define GRID  512
#define NREP  8                       // histogram replicas (~1 per XCD)
#define ROUNDS (NTOK / 4 / (BLOCK * GRID))   // = 8 int4 rounds per thread
#define CNT_SHIFT 39
#define SUM_MASK ((1ULL << CNT_SHIFT) - 1)
#define FXP_SCALE 4096.0f             // 2^12 fixed point for loss sums
#define INV_FXP   (1.0f / 4096.0f)

// ws layout:
//   [0, NREP*NPROP)  u64  packed replicas: (count << 39) | fixedpoint_sum
//   next float       g_total
//   next uint        g_ticket
// out layout: out[0]=stratified, out[1]=unweighted, out[2..2+NPROP)=new_freq

__global__ __launch_bounds__(BLOCK) void fused_kernel(
    const int* __restrict__ ids, const float* __restrict__ losses,
    const float* __restrict__ prop_freq, const int* __restrict__ d_bc,
    unsigned long long* __restrict__ g_rep, float* __restrict__ g_total,
    unsigned int* __restrict__ g_ticket, float* __restrict__ out)
{
    __shared__ int   s_cnt[NPROP];
    __shared__ float s_sum[NPROP];
    __shared__ float s_red_raw[16];
    __shared__ float s_red_dot[16];
    __shared__ int   s_last;

    for (int i = threadIdx.x; i < NPROP; i += BLOCK) {
        s_cnt[i] = 0;
        s_sum[i] = 0.0f;
    }
    __syncthreads();

    const int4*   ids4 = (const int4*)ids;
    const float4* ls4  = (const float4*)losses;
    const int tid    = blockIdx.x * BLOCK + threadIdx.x;
    const int STRIDE = GRID * BLOCK;

    float lt = 0.0f;

    // software pipeline: batches of 4 int4/float4 pairs
    int4 ida[4]; float4 la[4];
#pragma unroll
    for (int u = 0; u < 4; ++u) {
        int i = tid + u * STRIDE;
        ida[u] = ids4[i];
        la[u]  = ls4[i];
    }

#pragma unroll
    for (int b = 1; b < ROUNDS / 4; ++b) {
        int4 idb[4]; float4 lb[4];
#pragma unroll
        for (int u = 0; u < 4; ++u) {
            int i = tid + (b * 4 + u) * STRIDE;
            idb[u] = ids4[i];
            lb[u]  = ls4[i];
        }
#pragma unroll
        for (int u = 0; u < 4; ++u) {
            atomicAdd(&s_cnt[ida[u].x], 1); atomicAdd(&s_sum[ida[u].x], la[u].x);
            atomicAdd(&s_cnt[ida[u].y], 1); atomicAdd(&s_sum[ida[u].y], la[u].y);
            atomicAdd(&s_cnt[ida[u].z], 1); atomicAdd(&s_sum[ida[u].z], la[u].z);
            atomicAdd(&s_cnt[ida[u].w], 1); atomicAdd(&s_sum[ida[u].w], la[u].w);
            lt += (la[u].x + la[u].y) + (la[u].z + la[u].w);
        }
#pragma unroll
        for (int u = 0; u < 4; ++u) { ida[u] = idb[u]; la[u] = lb[u]; }
    }
    // drain final batch
#pragma unroll
    for (int u = 0; u < 4; ++u) {
        atomicAdd(&s_cnt[ida[u].x], 1); atomicAdd(&s_sum[ida[u].x], la[u].x);
        atomicAdd(&s_cnt[ida[u].y], 1); atomicAdd(&s_sum[ida[u].y], la[u].y);
        atomicAdd(&s_cnt[ida[u].z], 1); atomicAdd(&s_sum[ida[u].z], la[u].z);
        atomicAdd(&s_cnt[ida[u].w], 1); atomicAdd(&s_sum[ida[u].w], la[u].w);
        lt += (la[u].x + la[u].y) + (la[u].z + la[u].w);
    }

    // wave64 reduce the unweighted total, one global atomic per wave
    for (int off = 32; off > 0; off >>= 1)
        lt += __shfl_down(lt, off, 64);
    if ((threadIdx.x & 63) == 0)
        atomicAdd(g_total, lt);

    __syncthreads();

    // flush: one packed u64 atomic per present bin, into this block's replica
    unsigned long long* rep = g_rep + (unsigned)(blockIdx.x & (NREP - 1)) * NPROP;
    for (int i = threadIdx.x; i < NPROP; i += BLOCK) {
        int c = s_cnt[i];
        if (c != 0) {
            float s = s_sum[i];
            unsigned long long fx = (unsigned long long)(s * FXP_SCALE + 0.5f);
            atomicAdd(&rep[i], ((unsigned long long)(unsigned)c << CNT_SHIFT) | fx);
        }
    }

    __threadfence();
    if (threadIdx.x == 0) {
        unsigned old = atomicAdd(g_ticket, 1u);
        s_last = (old == (unsigned)(GRID - 1));
    }
    __syncthreads();
    if (!s_last) return;

    // ---- finalize: only the last-finished block runs this ----
    const int bc_i = d_bc[0];
    const float bc = (float)bc_i;
    const float ramp = fminf(1.0f, (bc - 1000.0f) / 200.0f);
    const float frac = bc / 3000.0f;

    float acc_raw = 0.0f;
    float acc_dot = 0.0f;

    for (int p = threadIdx.x; p < NPROP; p += BLOCK) {
        unsigned long long v = 0;
#pragma unroll
        for (int r = 0; r < NREP; ++r)
            v += __hip_atomic_load(&g_rep[r * NPROP + p],
                                   __ATOMIC_RELAXED, __HIP_MEMORY_SCOPE_AGENT);
        float cnt  = (float)(unsigned)(v >> CNT_SHIFT);
        float sumf = (float)(v & SUM_MASK) * INV_FXP;
        bool present = cnt > 0.0f;

        float mean_loss = present ? sumf / fmaxf(cnt, 1.0f) : 0.0f;
        float batch_freq = cnt / ((float)NTOK + 1e-6f);
        float new_freq = prop_freq[p] * 0.99f + (present ? 0.01f * batch_freq : 0.0f);
        out[2 + p] = new_freq;

        float freq_cl = fmaxf(new_freq, 1e-5f);
        float raw = 1.0f / sqrtf(freq_cl + 1e-6f);
        raw = 1.0f + ramp * (raw - 1.0f);
        raw = fminf(30.0f, raw);
        if (bc_i <= 3000) raw = raw * frac + (1.0f - frac);
        if (bc_i <= 1000) raw = 1.0f;

        float w = present ? raw : 0.0f;
        acc_raw += w;
        acc_dot += mean_loss * w;
    }

    for (int off = 32; off > 0; off >>= 1) {
        acc_raw += __shfl_down(acc_raw, off, 64);
        acc_dot += __shfl_down(acc_dot, off, 64);
    }
    int wave = threadIdx.x >> 6;
    if ((threadIdx.x & 63) == 0) {
        s_red_raw[wave] = acc_raw;
        s_red_dot[wave] = acc_dot;
    }
    __syncthreads();
    if (threadIdx.x == 0) {
        float t_raw = 0.0f, t_dot = 0.0f;
        for (int i = 0; i < BLOCK / 64; ++i) {
            t_raw += s_red_raw[i];
            t_dot += s_red_dot[i];
        }
        float total = __hip_atomic_load(g_total, __ATOMIC_RELAXED, __HIP_MEMORY_SCOPE_AGENT);
        out[0] = t_dot / (t_raw + 1e-6f);     // stratified_loss
        out[1] = total / (float)NTOK;         // unweighted_loss
    }
}

extern "C" void kernel_launch(void* const* d_in, const int* in_sizes, int n_in,
                              void* d_out, int out_size, void* d_ws, size_t ws_size,
                              hipStream_t stream) {
    const int*   ids       = (const int*)d_in[0];
    const float* losses    = (const float*)d_in[1];
    const float* prop_freq = (const float*)d_in[2];
    const int*   d_bc      = (const int*)d_in[3];
    float* out = (float*)d_out;

    unsigned long long* g_rep = (unsigned long long*)d_ws;
    float*    g_total  = (float*)(g_rep + NREP * NPROP);
    unsigned* g_ticket = (unsigned*)(g_total + 1);

    // zero replicas + total + ticket in one async memset (graph-capturable)
    size_t zero_bytes = (size_t)NREP * NPROP * 8 + 8;
    hipMemsetAsync(d_ws, 0, zero_bytes, stream);

    fused_kernel<<<GRID, BLOCK, 0, stream>>>(ids, losses, prop_freq, d_bc,
                                             g_rep, g_total, g_ticket, out);
}

// Round 3
// 160.759 us; speedup vs baseline: 2.1943x; 2.1943x over previous
//
#include <hip/hip_runtime.h>

// Problem constants (match reference)
#define NPROP 4096
#define NTOK  16777216
#define BLOCK 1024
#define GRID  512
#define NREP  8
#define STRIDE (GRID * BLOCK)
#define ROUNDS (NTOK / 4 / STRIDE)       // 8 int4 rounds per thread
#define CNT_SHIFT 39
#define SUM_MASK ((1ULL << CNT_SHIFT) - 1)
#define FXP_SCALE 4096.0f                // 2^12 fixed point for losses
#define INV_FXP   (1.0f / 4096.0f)

// ws layout: [0, NREP*NPROP) u64 packed replicas: (count << 39) | fxp_sum
// out layout: out[0]=stratified, out[1]=unweighted, out[2..2+NPROP)=new_freq
//
// Packing budget: per-block cnt <= 32768, fxp <= 32768*5*4096 = 6.7e8 < 2^39.
// Global replica: 64 blocks -> cnt <= 2^21 < 2^25 field, fxp <= 4.3e10 < 2^39. OK.

__global__ __launch_bounds__(BLOCK) void hist_kernel(
    const int* __restrict__ ids, const float* __restrict__ losses,
    unsigned long long* __restrict__ g_rep)
{
    __shared__ unsigned long long s_hist[NPROP];
    for (int i = threadIdx.x; i < NPROP; i += BLOCK) s_hist[i] = 0ULL;
    __syncthreads();

    const int4*   ids4 = (const int4*)ids;
    const float4* ls4  = (const float4*)losses;
    const int tid = blockIdx.x * BLOCK + threadIdx.x;

    // ONE u64 LDS atomic per token: (1<<39) | round(loss * 4096)
#pragma unroll 2
    for (int b = 0; b < ROUNDS; ++b) {
        int i = tid + b * STRIDE;
        int4   id = ids4[i];
        float4 l  = ls4[i];
        atomicAdd(&s_hist[id.x],
                  (1ULL << CNT_SHIFT) | (unsigned long long)(unsigned)(l.x * FXP_SCALE + 0.5f));
        atomicAdd(&s_hist[id.y],
                  (1ULL << CNT_SHIFT) | (unsigned long long)(unsigned)(l.y * FXP_SCALE + 0.5f));
        atomicAdd(&s_hist[id.z],
                  (1ULL << CNT_SHIFT) | (unsigned long long)(unsigned)(l.z * FXP_SCALE + 0.5f));
        atomicAdd(&s_hist[id.w],
                  (1ULL << CNT_SHIFT) | (unsigned long long)(unsigned)(l.w * FXP_SCALE + 0.5f));
    }

    __syncthreads();
    // flush: LDS word is already in replica format — one u64 atomic per bin
    unsigned long long* rep = g_rep + (unsigned)(blockIdx.x & (NREP - 1)) * NPROP;
    for (int i = threadIdx.x; i < NPROP; i += BLOCK) {
        unsigned long long v = s_hist[i];
        if (v) atomicAdd(&rep[i], v);
    }
}

__global__ __launch_bounds__(1024) void finalize_kernel(
    const unsigned long long* __restrict__ g_rep,
    const float* __restrict__ prop_freq, const int* __restrict__ d_bc,
    float* __restrict__ out)
{
    __shared__ float s_raw[16], s_dot[16], s_tot[16];

    const int bc_i = d_bc[0];
    const float bc = (float)bc_i;
    const float ramp = fminf(1.0f, (bc - 1000.0f) / 200.0f);
    const float frac = bc / 3000.0f;

    float a_raw = 0.0f, a_dot = 0.0f, a_tot = 0.0f;

    for (int p = threadIdx.x; p < NPROP; p += 1024) {
        unsigned long long v = 0;
#pragma unroll
        for (int r = 0; r < NREP; ++r)
            v += g_rep[r * NPROP + p];

        float cnt  = (float)(unsigned)(v >> CNT_SHIFT);
        float sumf = (float)(v & SUM_MASK) * INV_FXP;
        bool present = cnt > 0.0f;
        a_tot += sumf;

        float mean_loss = present ? sumf / fmaxf(cnt, 1.0f) : 0.0f;
        float batch_freq = cnt / ((float)NTOK + 1e-6f);
        float new_freq = prop_freq[p] * 0.99f + (present ? 0.01f * batch_freq : 0.0f);
        out[2 + p] = new_freq;

        float freq_cl = fmaxf(new_freq, 1e-5f);
        float raw = 1.0f / sqrtf(freq_cl + 1e-6f);
        raw = 1.0f + ramp * (raw - 1.0f);
        raw = fminf(30.0f, raw);
        if (bc_i <= 3000) raw = raw * frac + (1.0f - frac);
        if (bc_i <= 1000) raw = 1.0f;

        float w = present ? raw : 0.0f;
        a_raw += w;
        a_dot += mean_loss * w;
    }

    for (int off = 32; off > 0; off >>= 1) {
        a_raw += __shfl_down(a_raw, off, 64);
        a_dot += __shfl_down(a_dot, off, 64);
        a_tot += __shfl_down(a_tot, off, 64);
    }
    int wave = threadIdx.x >> 6;
    if ((threadIdx.x & 63) == 0) {
        s_raw[wave] = a_raw;
        s_dot[wave] = a_dot;
        s_tot[wave] = a_tot;
    }
    __syncthreads();
    if (threadIdx.x == 0) {
        float t_raw = 0.0f, t_dot = 0.0f, t_tot = 0.0f;
        for (int i = 0; i < 16; ++i) {
            t_raw += s_raw[i];
            t_dot += s_dot[i];
            t_tot += s_tot[i];
        }
        out[0] = t_dot / (t_raw + 1e-6f);   // stratified_loss
        out[1] = t_tot / (float)NTOK;       // unweighted_loss
    }
}

extern "C" void kernel_launch(void* const* d_in, const int* in_sizes, int n_in,
                              void* d_out, int out_size, void* d_ws, size_t ws_size,
                              hipStream_t stream) {
    const int*   ids       = (const int*)d_in[0];
    const float* losses    = (const float*)d_in[1];
    const float* prop_freq = (const float*)d_in[2];
    const int*   d_bc      = (const int*)d_in[3];
    float* out = (float*)d_out;

    unsigned long long* g_rep = (unsigned long long*)d_ws;

    // zero replicas (ws is re-poisoned to 0xAA before every timed launch)
    hipMemsetAsync(d_ws, 0, (size_t)NREP * NPROP * 8, stream);

    hist_kernel<<<GRID, BLOCK, 0, stream>>>(ids, losses, g_rep);
    finalize_kernel<<<1, 1024, 0, stream>>>(g_rep, prop_freq, d_bc, out);
}